// Round 3
// baseline (11666.502 us; speedup 1.0000x reference)
//
#include <hip/hip_runtime.h>
#include <math.h>

#define BQ 8
#define PP 196
#define DD 2048
#define AA 700
#define HH 700
#define EE 700
#define VV 30000
#define NSTEP 30
#define G4 2800
#define NA 2748    // att2(700) + gLin(2048)
#define KD 3448    // emb(700) + awe(2048) + h(700)

#define NBLK 768
#define NW (NBLK * 4)

#define KSA 32
#define KRA 22
#define NCBA 11

#define KSD 32
#define KRD 108
#define NCBD 11

#define KSE 6
#define KRE 117
#define NCBE 118

__device__ __forceinline__ float sigm(float x) { return 1.f / (1.f + expf(-x)); }

__device__ unsigned g_gen = 0;

__device__ __forceinline__ void gsync(unsigned* flags, unsigned& epoch) {
    const int tid = threadIdx.x;
    __syncthreads();
    ++epoch;
    if (blockIdx.x == 0) {
        bool done = false;
        do {
            bool ok = true;
            for (int i = 1 + tid; i < NBLK; i += 256)
                ok = ok && (__hip_atomic_load(&flags[i], __ATOMIC_RELAXED,
                                              __HIP_MEMORY_SCOPE_AGENT) == epoch);
            done = (__syncthreads_and(ok ? 1 : 0) != 0);
            if (!done) __builtin_amdgcn_s_sleep(2);
        } while (!done);
        __threadfence();
        if (tid == 0)
            __hip_atomic_store(&g_gen, epoch, __ATOMIC_RELEASE, __HIP_MEMORY_SCOPE_AGENT);
        __syncthreads();
    } else {
        if (tid == 0) {
            __threadfence();
            __hip_atomic_store(&flags[blockIdx.x], epoch, __ATOMIC_RELEASE,
                               __HIP_MEMORY_SCOPE_AGENT);
            while (__hip_atomic_load(&g_gen, __ATOMIC_RELAXED,
                                     __HIP_MEMORY_SCOPE_AGENT) != epoch)
                __builtin_amdgcn_s_sleep(4);
            __threadfence();
        }
        __syncthreads();
    }
}

// -------- prologue: mean over pixels --------
__global__ __launch_bounds__(256) void k_mean(const float* __restrict__ enc,
                                              float* __restrict__ mean) {
    int b = blockIdx.x >> 3;
    int d = ((blockIdx.x & 7) << 8) + threadIdx.x;
    const float* p = enc + (size_t)b * PP * DD + d;
    float s = 0.f;
    for (int i = 0; i < PP; i++) s += p[(size_t)i * DD];
    mean[b * DD + d] = s * (1.0f / PP);
}

// -------- prologue: h0 / c0 --------
__global__ __launch_bounds__(256) void k_init_hc(const float* __restrict__ mean,
    const float* __restrict__ Wh, const float* __restrict__ bh,
    const float* __restrict__ Wc, const float* __restrict__ bc,
    float* __restrict__ h, float* __restrict__ c) {
    __shared__ float X[BQ][DD];
    __shared__ float red[4][64][BQ];
    int tid = threadIdx.x;
    for (int i = tid; i < BQ * DD; i += 256) X[i / DD][i % DD] = mean[i];
    __syncthreads();
    int j = blockIdx.x * 64 + (tid & 63);
    int kq = tid >> 6;
    float acc[BQ];
    #pragma unroll
    for (int b = 0; b < BQ; b++) acc[b] = 0.f;
    if (j < 2 * HH) {
        bool isH = j < HH;
        int col = isH ? j : j - HH;
        const float* wp = (isH ? Wh : Wc) + (size_t)(kq * 512) * HH + col;
        for (int k = kq * 512; k < kq * 512 + 512; k++) {
            float wv = *wp; wp += HH;
            #pragma unroll
            for (int b = 0; b < BQ; b++) acc[b] += X[b][k] * wv;
        }
    }
    #pragma unroll
    for (int b = 0; b < BQ; b++) red[kq][tid & 63][b] = acc[b];
    __syncthreads();
    for (int idx = tid; idx < 512; idx += 256) {
        int jj = idx >> 3, b = idx & 7;
        int jg = blockIdx.x * 64 + jj;
        if (jg >= 2 * HH) continue;
        float s = red[0][jj][b] + red[1][jj][b] + red[2][jj][b] + red[3][jj][b];
        bool isH = jg < HH;
        int col = isH ? jg : jg - HH;
        s += isH ? bh[col] : bc[col];
        (isH ? h : c)[b * HH + col] = s;
    }
}

// -------- prologue: att1 = enc_flat @ W_enc_att + b --------
__global__ __launch_bounds__(256) void k_att1(const float* __restrict__ Aenc,
    const float* __restrict__ W, const float* __restrict__ bias,
    float* __restrict__ att1) {
    const int M = BQ * PP; // 1568
    __shared__ float As[16][68];
    __shared__ float Bs[16][68];
    int bm = blockIdx.x, bn = blockIdx.y;
    int tid = threadIdx.x;
    int tx = tid & 15, ty = tid >> 4;
    float acc[4][4] = {};
    for (int kt = 0; kt < DD; kt += 16) {
        {
            int row = tid >> 2, k4 = (tid & 3) * 4;
            int grow = bm * 64 + row;
            float4 v = make_float4(0.f, 0.f, 0.f, 0.f);
            if (grow < M) v = *(const float4*)&Aenc[(size_t)grow * DD + kt + k4];
            As[k4 + 0][row] = v.x; As[k4 + 1][row] = v.y;
            As[k4 + 2][row] = v.z; As[k4 + 3][row] = v.w;
        }
        {
            int rk = tid >> 4, n4 = (tid & 15) * 4;
            int col = bn * 64 + n4;
            float4 wv = make_float4(0.f, 0.f, 0.f, 0.f);
            if (col < AA) wv = *(const float4*)&W[(size_t)(kt + rk) * AA + col];
            *(float4*)&Bs[rk][n4] = wv;
        }
        __syncthreads();
        #pragma unroll
        for (int k = 0; k < 16; k++) {
            float4 a  = *(const float4*)&As[k][ty * 4];
            float4 bv = *(const float4*)&Bs[k][tx * 4];
            float av[4] = {a.x, a.y, a.z, a.w};
            float bb[4] = {bv.x, bv.y, bv.z, bv.w};
            #pragma unroll
            for (int i = 0; i < 4; i++)
                #pragma unroll
                for (int j = 0; j < 4; j++) acc[i][j] += av[i] * bb[j];
        }
        __syncthreads();
    }
    for (int i = 0; i < 4; i++) {
        int row = bm * 64 + ty * 4 + i;
        if (row >= M) continue;
        for (int j = 0; j < 4; j++) {
            int col = bn * 64 + tx * 4 + j;
            if (col < AA) att1[(size_t)row * AA + col] = acc[i][j] + bias[col];
        }
    }
}

// ==================== persistent decode kernel ====================
__global__ __launch_bounds__(256, 3) void k_decode(
    const float* __restrict__ enc, const float* __restrict__ emb,
    const float* __restrict__ Wda, const float* __restrict__ bda,
    const float* __restrict__ Wfull,
    const float* __restrict__ Wih, const float* __restrict__ bih,
    const float* __restrict__ Whh, const float* __restrict__ bhh,
    const float* __restrict__ Wfb, const float* __restrict__ bfb,
    const float* __restrict__ Wfc, const float* __restrict__ bfc,
    const float* __restrict__ att1,
    float* __restrict__ pA, float* __restrict__ pDE,
    float* __restrict__ att2, float* __restrict__ gate,
    float* __restrict__ awe, float* __restrict__ ebuf,
    float* __restrict__ hbuf, float* __restrict__ cbuf,
    float* __restrict__ argval, int* __restrict__ argidx,
    int* __restrict__ prev, unsigned* flags,
    float* __restrict__ preds, float* __restrict__ oalpha)
{
    __shared__ float s_red[4 * 64 * 33];   // 33792 B (reused by several stages)
    __shared__ float s_X[KRE * 8];         // 3744 B
    __shared__ float s_al[PP];
    __shared__ float s_rb[8];
    __shared__ int   s_prev[8];
    __shared__ unsigned s_ep;

    const int tid  = threadIdx.x;
    const int blk  = blockIdx.x;
    const int lane = tid & 63;
    const int w    = tid >> 6;

    if (tid == 0) s_ep = __hip_atomic_load(&g_gen, __ATOMIC_RELAXED, __HIP_MEMORY_SCOPE_AGENT);
    __syncthreads();
    unsigned epoch = s_ep;

    for (int t = 0; t < NSTEP; ++t) {

        // ---------- stage A: pA partials of h @ [W_dec_att | W_fbeta] ----------
        if (blk < NCBA * KSA) {
            int cb = blk % NCBA, kc = blk / NCBA;
            int k0 = kc * KRA;
            int kr = min(KRA, AA - k0);
            for (int i = tid; i < kr * 8; i += 256) {
                int k = i >> 3, b = i & 7;
                s_X[k * 8 + b] = hbuf[b * HH + k0 + k];
            }
            __syncthreads();
            int ka = (w * kr) >> 2, kb = ((w + 1) * kr) >> 2;
            int c0 = cb * 256 + lane * 4;
            float acc[8][4] = {};
            if (c0 < NA) {
                const float* W; int col, ld;
                if (c0 < AA) { W = Wda; col = c0;      ld = AA; }
                else         { W = Wfb; col = c0 - AA; ld = DD; }
                const float* wp = W + (size_t)(k0 + ka) * ld + col;
                #pragma unroll 2
                for (int k = ka; k < kb; ++k) {
                    float4 wv = *(const float4*)wp; wp += ld;
                    float4 xa = *(const float4*)&s_X[k * 8];
                    float4 xb = *(const float4*)&s_X[k * 8 + 4];
                    float xv[8] = {xa.x, xa.y, xa.z, xa.w, xb.x, xb.y, xb.z, xb.w};
                    #pragma unroll
                    for (int b = 0; b < 8; b++) {
                        acc[b][0] += xv[b] * wv.x; acc[b][1] += xv[b] * wv.y;
                        acc[b][2] += xv[b] * wv.z; acc[b][3] += xv[b] * wv.w;
                    }
                }
            }
            float* rr = &s_red[(w * 64 + lane) * 33];
            #pragma unroll
            for (int b = 0; b < 8; b++)
                #pragma unroll
                for (int cc = 0; cc < 4; cc++) rr[cc * 8 + b] = acc[b][cc];
            __syncthreads();
            for (int idx = tid; idx < 2048; idx += 256) {
                int cl = idx >> 3, b = idx & 7;
                int gc = cb * 256 + cl;
                if (gc < NA) {
                    int ln = cl >> 2, cc = cl & 3;
                    float s = s_red[(0 * 64 + ln) * 33 + cc * 8 + b]
                            + s_red[(1 * 64 + ln) * 33 + cc * 8 + b]
                            + s_red[(2 * 64 + ln) * 33 + cc * 8 + b]
                            + s_red[(3 * 64 + ln) * 33 + cc * 8 + b];
                    pA[((size_t)kc * NA + gc) * 8 + b] = s;
                }
            }
        }
        gsync(flags, epoch);

        // ---------- stage A2: reduce pA -> att2, gate; block NBLK-1: prev ----------
        if (blk == NBLK - 1) {
            if (t == 0) {
                if (tid < 8) prev[tid] = 1;
            } else {
                int b = tid >> 5, l = tid & 31;
                float bv = -3.4e38f; int bi = 0x7fffffff;
                for (int vb = l; vb < NW; vb += 32) {
                    float v = argval[(size_t)vb * 8 + b];
                    int ix = argidx[vb * 8 + b];
                    if (v > bv || (v == bv && ix < bi)) { bv = v; bi = ix; }
                }
                #pragma unroll
                for (int off = 16; off; off >>= 1) {
                    float ov = __shfl_down(bv, off, 32);
                    int   oi = __shfl_down(bi, off, 32);
                    if (ov > bv || (ov == bv && oi < bi)) { bv = ov; bi = oi; }
                }
                if (l == 0) prev[b] = bi;
            }
        } else {
            int gid = blk * 256 + tid;
            if (gid < NA * 8) {
                int col = gid >> 3, b = gid & 7;
                float s = 0.f;
                #pragma unroll
                for (int kc = 0; kc < KSA; kc++) s += pA[((size_t)kc * NA + col) * 8 + b];
                if (col < AA) att2[b * AA + col] = s + bda[col];
                else          gate[b * DD + (col - AA)] = sigm(s + bfb[col - AA]);
            }
        }
        gsync(flags, epoch);

        // ---------- stage B: e[b][p] = relu(att1+att2) . Wfull ----------
        {
            int wid = blk * 4 + w;
            if (wid < BQ * PP) {
                int b = wid / PP, p = wid % PP;
                const float* ap = att1 + (size_t)(b * PP + p) * AA;
                const float* a2 = att2 + b * AA;
                float s = 0.f;
                for (int f4 = lane; f4 < 175; f4 += 64) {
                    float4 av = *(const float4*)(ap + f4 * 4);
                    float4 tv = *(const float4*)(a2 + f4 * 4);
                    float4 wv = *(const float4*)(Wfull + f4 * 4);
                    float v0 = av.x + tv.x, v1 = av.y + tv.y;
                    float v2 = av.z + tv.z, v3 = av.w + tv.w;
                    s += fmaxf(v0, 0.f) * wv.x + fmaxf(v1, 0.f) * wv.y
                       + fmaxf(v2, 0.f) * wv.z + fmaxf(v3, 0.f) * wv.w;
                }
                #pragma unroll
                for (int off = 32; off; off >>= 1) s += __shfl_down(s, off, 64);
                if (lane == 0) ebuf[b * PP + p] = s;
            }
        }
        gsync(flags, epoch);

        // ---------- stage C: softmax(e) -> alpha; awe = gate * (alpha @ enc) ----------
        if (blk < 64) {
            int b = blk >> 3, dc = blk & 7;
            float v = (tid < PP) ? ebuf[b * PP + tid] : -3.4e38f;
            float m = v;
            #pragma unroll
            for (int off = 32; off; off >>= 1) m = fmaxf(m, __shfl_down(m, off, 64));
            if (lane == 0) s_rb[w] = m;
            __syncthreads();
            m = fmaxf(fmaxf(s_rb[0], s_rb[1]), fmaxf(s_rb[2], s_rb[3]));
            float ex = (tid < PP) ? expf(v - m) : 0.f;
            float s2 = ex;
            #pragma unroll
            for (int off = 32; off; off >>= 1) s2 += __shfl_down(s2, off, 64);
            if (lane == 0) s_rb[4 + w] = s2;
            __syncthreads();
            float den = s_rb[4] + s_rb[5] + s_rb[6] + s_rb[7];
            if (tid < PP) {
                float al = ex / den;
                s_al[tid] = al;
                if (dc == 0) oalpha[((size_t)b * NSTEP + t) * PP + tid] = al;
            }
            __syncthreads();
            int d = dc * 256 + lane * 4;
            int p0 = w * 49;
            float4 acc = make_float4(0.f, 0.f, 0.f, 0.f);
            const float* ep = enc + (size_t)(b * PP + p0) * DD + d;
            for (int p = 0; p < 49; ++p) {
                float a = s_al[p0 + p];
                float4 ev = *(const float4*)ep; ep += DD;
                acc.x += a * ev.x; acc.y += a * ev.y;
                acc.z += a * ev.z; acc.w += a * ev.w;
            }
            *(float4*)&s_red[w * 256 + lane * 4] = acc;
            __syncthreads();
            {
                float tot = s_red[0 * 256 + tid] + s_red[1 * 256 + tid]
                          + s_red[2 * 256 + tid] + s_red[3 * 256 + tid];
                int dg = dc * 256 + tid;
                awe[b * DD + dg] = gate[b * DD + dg] * tot;
            }
        }
        gsync(flags, epoch);

        // ---------- stage D1: pD partials of [emb;awe;h] @ [W_ih;W_hh] ----------
        if (blk < NCBD * KSD) {
            int cb = blk % NCBD, kc = blk / NCBD;
            int k0 = kc * KRD;
            int kr = min(KRD, KD - k0);
            if (tid < 8) s_prev[tid] = prev[tid];
            __syncthreads();
            for (int i = tid; i < kr * 8; i += 256) {
                int k = i >> 3, b = i & 7;
                int kg = k0 + k;
                float x;
                if (kg < EE)            x = emb[(size_t)s_prev[b] * EE + kg];
                else if (kg < EE + DD)  x = awe[b * DD + (kg - EE)];
                else                    x = hbuf[b * HH + (kg - EE - DD)];
                s_X[k * 8 + b] = x;
            }
            __syncthreads();
            int ka = (w * kr) >> 2, kb2 = ((w + 1) * kr) >> 2;
            int c0 = cb * 256 + lane * 4;
            float acc[8][4] = {};
            if (c0 < G4) {
                #pragma unroll 2
                for (int k = ka; k < kb2; ++k) {
                    int kg = k0 + k;
                    const float* wp = (kg < EE + DD)
                        ? (Wih + (size_t)kg * G4 + c0)
                        : (Whh + (size_t)(kg - EE - DD) * G4 + c0);
                    float4 wv = *(const float4*)wp;
                    float4 xa = *(const float4*)&s_X[k * 8];
                    float4 xb = *(const float4*)&s_X[k * 8 + 4];
                    float xv[8] = {xa.x, xa.y, xa.z, xa.w, xb.x, xb.y, xb.z, xb.w};
                    #pragma unroll
                    for (int b = 0; b < 8; b++) {
                        acc[b][0] += xv[b] * wv.x; acc[b][1] += xv[b] * wv.y;
                        acc[b][2] += xv[b] * wv.z; acc[b][3] += xv[b] * wv.w;
                    }
                }
            }
            float* rr = &s_red[(w * 64 + lane) * 33];
            #pragma unroll
            for (int b = 0; b < 8; b++)
                #pragma unroll
                for (int cc = 0; cc < 4; cc++) rr[cc * 8 + b] = acc[b][cc];
            __syncthreads();
            for (int idx = tid; idx < 2048; idx += 256) {
                int cl = idx >> 3, b = idx & 7;
                int gc = cb * 256 + cl;
                if (gc < G4) {
                    int ln = cl >> 2, cc = cl & 3;
                    float s = s_red[(0 * 64 + ln) * 33 + cc * 8 + b]
                            + s_red[(1 * 64 + ln) * 33 + cc * 8 + b]
                            + s_red[(2 * 64 + ln) * 33 + cc * 8 + b]
                            + s_red[(3 * 64 + ln) * 33 + cc * 8 + b];
                    pDE[((size_t)kc * G4 + gc) * 8 + b] = s;
                }
            }
        }
        gsync(flags, epoch);

        // ---------- stage D2: reduce pD + LSTM cell ----------
        if (blk < 88) {
            int p = tid & 63, kcg = tid >> 6;
            int gid = blk * 64 + p;
            float g0 = 0.f, g1 = 0.f, g2 = 0.f, g3 = 0.f;
            if (gid < BQ * HH) {
                int j = gid >> 3, b = gid & 7;
                #pragma unroll
                for (int u = 0; u < 8; ++u) {
                    const float* base = pDE + (size_t)(kcg * 8 + u) * G4 * 8;
                    g0 += base[(size_t)(j) * 8 + b];
                    g1 += base[(size_t)(AA + j) * 8 + b];
                    g2 += base[(size_t)(2 * AA + j) * 8 + b];
                    g3 += base[(size_t)(3 * AA + j) * 8 + b];
                }
            }
            float* sd = &s_red[(kcg * 64 + p) * 4];
            sd[0] = g0; sd[1] = g1; sd[2] = g2; sd[3] = g3;
            __syncthreads();
            if (tid < 64) {
                int gid2 = blk * 64 + tid;
                if (gid2 < BQ * HH) {
                    int j = gid2 >> 3, b = gid2 & 7;
                    float s0 = s_red[(0*64+tid)*4+0] + s_red[(1*64+tid)*4+0]
                             + s_red[(2*64+tid)*4+0] + s_red[(3*64+tid)*4+0]
                             + bih[j] + bhh[j];
                    float s1 = s_red[(0*64+tid)*4+1] + s_red[(1*64+tid)*4+1]
                             + s_red[(2*64+tid)*4+1] + s_red[(3*64+tid)*4+1]
                             + bih[AA + j] + bhh[AA + j];
                    float s2 = s_red[(0*64+tid)*4+2] + s_red[(1*64+tid)*4+2]
                             + s_red[(2*64+tid)*4+2] + s_red[(3*64+tid)*4+2]
                             + bih[2 * AA + j] + bhh[2 * AA + j];
                    float s3 = s_red[(0*64+tid)*4+3] + s_red[(1*64+tid)*4+3]
                             + s_red[(2*64+tid)*4+3] + s_red[(3*64+tid)*4+3]
                             + bih[3 * AA + j] + bhh[3 * AA + j];
                    float ig = sigm(s0), fg = sigm(s1), gg = tanhf(s2), og = sigm(s3);
                    float cn = fg * cbuf[b * HH + j] + ig * gg;
                    cbuf[b * HH + j] = cn;
                    hbuf[b * HH + j] = og * tanhf(cn);
                }
            }
        }
        gsync(flags, epoch);

        // ---------- stage E1: pE partials of h @ W_fc ----------
        if (blk < NCBE * KSE) {
            int cb = blk % NCBE, kc = blk / NCBE;
            int k0 = kc * KRE;
            int kr = min(KRE, AA - k0);
            for (int i = tid; i < kr * 8; i += 256) {
                int k = i >> 3, b = i & 7;
                s_X[k * 8 + b] = hbuf[b * HH + k0 + k];
            }
            __syncthreads();
            int ka = (w * kr) >> 2, kb = ((w + 1) * kr) >> 2;
            int c0 = cb * 256 + lane * 4;
            float acc[8][4] = {};
            if (c0 < VV) {
                const float* wp = Wfc + (size_t)(k0 + ka) * VV + c0;
                #pragma unroll 2
                for (int k = ka; k < kb; ++k) {
                    float4 wv = *(const float4*)wp; wp += VV;
                    float4 xa = *(const float4*)&s_X[k * 8];
                    float4 xb = *(const float4*)&s_X[k * 8 + 4];
                    float xv[8] = {xa.x, xa.y, xa.z, xa.w, xb.x, xb.y, xb.z, xb.w};
                    #pragma unroll
                    for (int b = 0; b < 8; b++) {
                        acc[b][0] += xv[b] * wv.x; acc[b][1] += xv[b] * wv.y;
                        acc[b][2] += xv[b] * wv.z; acc[b][3] += xv[b] * wv.w;
                    }
                }
            }
            float* rr = &s_red[(w * 64 + lane) * 33];
            #pragma unroll
            for (int b = 0; b < 8; b++)
                #pragma unroll
                for (int cc = 0; cc < 4; cc++) rr[cc * 8 + b] = acc[b][cc];
            __syncthreads();
            for (int idx = tid; idx < 2048; idx += 256) {
                int cl = idx >> 3, b = idx & 7;
                int gc = cb * 256 + cl;
                if (gc < VV) {
                    int ln = cl >> 2, cc = cl & 3;
                    float s = s_red[(0 * 64 + ln) * 33 + cc * 8 + b]
                            + s_red[(1 * 64 + ln) * 33 + cc * 8 + b]
                            + s_red[(2 * 64 + ln) * 33 + cc * 8 + b]
                            + s_red[(3 * 64 + ln) * 33 + cc * 8 + b];
                    pDE[((size_t)kc * VV + gc) * 8 + b] = s;
                }
            }
        }
        gsync(flags, epoch);

        // ---------- stage E2: reduce pE + b_fc -> preds, wave argmax partials ----------
        {
            float bv = -3.4e38f; int bi = 0x7fffffff;
            #pragma unroll
            for (int pass = 0; pass < 2; ++pass) {
                int gid = blk * 256 + tid + pass * (NBLK * 256);
                if (gid < VV * 8) {
                    int col = gid >> 3, b = gid & 7;
                    float s = bfc[col];
                    #pragma unroll
                    for (int kc = 0; kc < KSE; kc++)
                        s += pDE[((size_t)kc * VV + col) * 8 + b];
                    preds[((size_t)b * NSTEP + t) * VV + col] = s;
                    if (s > bv) { bv = s; bi = col; }
                }
            }
            #pragma unroll
            for (int off = 8; off < 64; off <<= 1) {
                float ov = __shfl_down(bv, off, 64);
                int   oi = __shfl_down(bi, off, 64);
                if (ov > bv || (ov == bv && oi < bi)) { bv = ov; bi = oi; }
            }
            if (lane < 8) {
                int wid = blk * 4 + w;
                argval[(size_t)wid * 8 + lane] = bv;
                argidx[wid * 8 + lane] = bi;
            }
        }
        // no barrier: E2 output (argval) first consumed in next step's A2,
        // next step's A touches only pA/hbuf (disjoint).
    }
}

extern "C" void kernel_launch(void* const* d_in, const int* in_sizes, int n_in,
                              void* d_out, int out_size, void* d_ws, size_t ws_size,
                              hipStream_t stream) {
    (void)in_sizes; (void)n_in; (void)out_size; (void)ws_size;
    const float* enc   = (const float*)d_in[0];
    const float* emb   = (const float*)d_in[2];
    const float* Wea   = (const float*)d_in[3];
    const float* bea   = (const float*)d_in[4];
    const float* Wda   = (const float*)d_in[5];
    const float* bda   = (const float*)d_in[6];
    const float* Wfull = (const float*)d_in[7];
    // d_in[8] = b_full (softmax-invariant, unused)
    const float* Wih   = (const float*)d_in[9];
    const float* bih   = (const float*)d_in[10];
    const float* Whh   = (const float*)d_in[11];
    const float* bhh   = (const float*)d_in[12];
    const float* Winh  = (const float*)d_in[13];
    const float* binh  = (const float*)d_in[14];
    const float* Winc  = (const float*)d_in[15];
    const float* binc  = (const float*)d_in[16];
    const float* Wfb   = (const float*)d_in[17];
    const float* bfb   = (const float*)d_in[18];
    const float* Wfc   = (const float*)d_in[19];
    const float* bfc   = (const float*)d_in[20];

    float* preds  = (float*)d_out;
    float* oalpha = preds + (size_t)BQ * NSTEP * VV;

    float* ws = (float*)d_ws;
    float* att1   = ws; ws += (size_t)BQ * PP * AA;    // 1,097,600
    float* pA     = ws; ws += (size_t)KSA * NA * 8;    //   703,488
    float* pDE    = ws; ws += (size_t)KSE * VV * 8;    // 1,440,000 (shared by pD: 716,800)
    float* att2   = ws; ws += 8 * AA;
    float* gate   = ws; ws += 8 * DD;
    float* awe    = ws; ws += 8 * DD;
    float* ebuf   = ws; ws += 8 * PP;
    float* hbuf   = ws; ws += 8 * HH;
    float* cbuf   = ws; ws += 8 * HH;
    float* argval = ws; ws += (size_t)NW * 8;
    int*   argidx = (int*)ws; ws += (size_t)NW * 8;
    int*   prev   = (int*)ws; ws += 16;
    unsigned* flags = (unsigned*)ws; ws += NBLK;
    float* mean = pDE;   // prologue-only; dead before pDE first written

    k_mean<<<64, 256, 0, stream>>>(enc, mean);
    k_init_hc<<<22, 256, 0, stream>>>(mean, Winh, binh, Winc, binc, hbuf, cbuf);
    k_att1<<<dim3(25, 11), 256, 0, stream>>>(enc, Wea, bea, att1);

    k_decode<<<NBLK, 256, 0, stream>>>(enc, emb, Wda, bda, Wfull,
        Wih, bih, Whh, bhh, Wfb, bfb, Wfc, bfc, att1,
        pA, pDE, att2, gate, awe, ebuf, hbuf, cbuf,
        argval, argidx, prev, flags, preds, oalpha);
}

// Round 4
// 1865.724 us; speedup vs baseline: 6.2531x; 6.2531x over previous
//
#include <hip/hip_runtime.h>
#include <math.h>

#define BQ 8
#define PP 196
#define DD 2048
#define AA 700
#define HH 700
#define EE 700
#define VV 30000
#define NSTEP 30
#define G4 2800
#define NA 2748    // A cols: att2(700) + gLin(2048)
#define KD 3448    // D1 virtual K: emb(700) + awe(2048) + h(700)

#define KSA 32
#define KRA 22
#define NCBA 11

#define KSD 32
#define KRD 108
#define NCBD 11

#define KSE 6
#define KRE 117
#define NCBE 118
#define NB2 235    // E2 blocks (argmax partials)

__device__ __forceinline__ float sigm(float x) { return 1.f / (1.f + expf(-x)); }

// -------- prologue: mean over pixels --------
__global__ __launch_bounds__(256) void k_mean(const float* __restrict__ enc,
                                              float* __restrict__ mean) {
    int b = blockIdx.x >> 3;
    int d = ((blockIdx.x & 7) << 8) + threadIdx.x;
    const float* p = enc + (size_t)b * PP * DD + d;
    float s = 0.f;
    for (int i = 0; i < PP; i++) s += p[(size_t)i * DD];
    mean[b * DD + d] = s * (1.0f / PP);
}

// -------- prologue: h0 / c0 --------
__global__ __launch_bounds__(256) void k_init_hc(const float* __restrict__ mean,
    const float* __restrict__ Wh, const float* __restrict__ bh,
    const float* __restrict__ Wc, const float* __restrict__ bc,
    float* __restrict__ h, float* __restrict__ c) {
    __shared__ float X[BQ][DD];
    __shared__ float red[4][64][BQ];
    int tid = threadIdx.x;
    for (int i = tid; i < BQ * DD; i += 256) X[i / DD][i % DD] = mean[i];
    __syncthreads();
    int j = blockIdx.x * 64 + (tid & 63);
    int kq = tid >> 6;
    float acc[BQ];
    #pragma unroll
    for (int b = 0; b < BQ; b++) acc[b] = 0.f;
    if (j < 2 * HH) {
        bool isH = j < HH;
        int col = isH ? j : j - HH;
        const float* wp = (isH ? Wh : Wc) + (size_t)(kq * 512) * HH + col;
        for (int k = kq * 512; k < kq * 512 + 512; k++) {
            float wv = *wp; wp += HH;
            #pragma unroll
            for (int b = 0; b < BQ; b++) acc[b] += X[b][k] * wv;
        }
    }
    #pragma unroll
    for (int b = 0; b < BQ; b++) red[kq][tid & 63][b] = acc[b];
    __syncthreads();
    for (int idx = tid; idx < 512; idx += 256) {
        int jj = idx >> 3, b = idx & 7;
        int jg = blockIdx.x * 64 + jj;
        if (jg >= 2 * HH) continue;
        float s = red[0][jj][b] + red[1][jj][b] + red[2][jj][b] + red[3][jj][b];
        bool isH = jg < HH;
        int col = isH ? jg : jg - HH;
        s += isH ? bh[col] : bc[col];
        (isH ? h : c)[b * HH + col] = s;
    }
}

// -------- prologue: att1 partials, k split 2 over blockIdx.z --------
__global__ __launch_bounds__(256) void k_att1(const float* __restrict__ Aenc,
    const float* __restrict__ W, float* __restrict__ out0,
    float* __restrict__ out1) {
    const int M = BQ * PP; // 1568
    __shared__ float As[16][68];
    __shared__ float Bs[16][68];
    int bm = blockIdx.x, bn = blockIdx.y, bz = blockIdx.z;
    int tid = threadIdx.x;
    int tx = tid & 15, ty = tid >> 4;
    float acc[4][4] = {};
    int kbeg = bz * 1024, kend = kbeg + 1024;
    for (int kt = kbeg; kt < kend; kt += 16) {
        {
            int row = tid >> 2, k4 = (tid & 3) * 4;
            int grow = bm * 64 + row;
            float4 v = make_float4(0.f, 0.f, 0.f, 0.f);
            if (grow < M) v = *(const float4*)&Aenc[(size_t)grow * DD + kt + k4];
            As[k4 + 0][row] = v.x; As[k4 + 1][row] = v.y;
            As[k4 + 2][row] = v.z; As[k4 + 3][row] = v.w;
        }
        {
            int rk = tid >> 4, n4 = (tid & 15) * 4;
            int col = bn * 64 + n4;
            float4 wv = make_float4(0.f, 0.f, 0.f, 0.f);
            if (col < AA) wv = *(const float4*)&W[(size_t)(kt + rk) * AA + col];
            *(float4*)&Bs[rk][n4] = wv;
        }
        __syncthreads();
        #pragma unroll
        for (int k = 0; k < 16; k++) {
            float4 a  = *(const float4*)&As[k][ty * 4];
            float4 bv = *(const float4*)&Bs[k][tx * 4];
            float av[4] = {a.x, a.y, a.z, a.w};
            float bb[4] = {bv.x, bv.y, bv.z, bv.w};
            #pragma unroll
            for (int i = 0; i < 4; i++)
                #pragma unroll
                for (int j = 0; j < 4; j++) acc[i][j] += av[i] * bb[j];
        }
        __syncthreads();
    }
    float* out = bz ? out1 : out0;
    for (int i = 0; i < 4; i++) {
        int row = bm * 64 + ty * 4 + i;
        if (row >= M) continue;
        for (int j = 0; j < 4; j++) {
            int col = bn * 64 + tx * 4 + j;
            if (col < AA) out[(size_t)row * AA + col] = acc[i][j];
        }
    }
}

// -------- prologue: att1 = part0 + part1 + bias --------
__global__ __launch_bounds__(256) void k_att1red(float* __restrict__ att1,
    const float* __restrict__ part, const float* __restrict__ bias) {
    size_t row = blockIdx.x;
    for (int c = threadIdx.x; c < AA; c += 256)
        att1[row * AA + c] += part[row * AA + c] + bias[c];
}

// -------- step A: pA[kc][b][col] partials of h @ [W_dec_att | W_fbeta];
//          extra block: prev-step argmax finalize --------
__global__ __launch_bounds__(256) void k_stepA(const float* __restrict__ h,
    const float* __restrict__ Wda, const float* __restrict__ Wfb,
    float* __restrict__ pA,
    const float* __restrict__ argval, const int* __restrict__ argidx,
    int* __restrict__ prev, int t) {
    int tid = threadIdx.x;
    if (blockIdx.x == NCBA * KSA) {
        int b = tid >> 5, l = tid & 31;
        if (b < 8) {
            if (t == 0) {
                if (l == 0) prev[b] = 1;
            } else {
                float bv = -3.4e38f; int bi = 0x7fffffff;
                for (int vb = l; vb < NB2; vb += 32) {
                    float v = argval[vb * 8 + b]; int ix = argidx[vb * 8 + b];
                    if (v > bv || (v == bv && ix < bi)) { bv = v; bi = ix; }
                }
                #pragma unroll
                for (int off = 16; off; off >>= 1) {
                    float ov = __shfl_down(bv, off, 32);
                    int   oi = __shfl_down(bi, off, 32);
                    if (ov > bv || (ov == bv && oi < bi)) { bv = ov; bi = oi; }
                }
                if (l == 0) prev[b] = bi;
            }
        }
        return;
    }
    __shared__ float s_X[KRA * 8];
    __shared__ float s_red[4 * 64 * 33];
    int cb = blockIdx.x % NCBA, kc = blockIdx.x / NCBA;
    int k0 = kc * KRA;
    int kr = min(KRA, AA - k0);
    for (int i = tid; i < kr * 8; i += 256) {
        int k = i >> 3, b = i & 7;
        s_X[k * 8 + b] = h[b * HH + k0 + k];
    }
    __syncthreads();
    int lane = tid & 63, w = tid >> 6;
    int ka = (w * kr) >> 2, kb = ((w + 1) * kr) >> 2;
    int c0 = cb * 256 + lane * 4;
    float acc[8][4] = {};
    if (c0 < NA) {
        const float* W; int col, ld;
        if (c0 < AA) { W = Wda; col = c0;      ld = AA; }
        else         { W = Wfb; col = c0 - AA; ld = DD; }
        const float* wp = W + (size_t)(k0 + ka) * ld + col;
        #pragma unroll 2
        for (int k = ka; k < kb; ++k) {
            float4 wv = *(const float4*)wp; wp += ld;
            float4 xa = *(const float4*)&s_X[k * 8];
            float4 xb = *(const float4*)&s_X[k * 8 + 4];
            float xv[8] = {xa.x, xa.y, xa.z, xa.w, xb.x, xb.y, xb.z, xb.w};
            #pragma unroll
            for (int b = 0; b < 8; b++) {
                acc[b][0] += xv[b] * wv.x; acc[b][1] += xv[b] * wv.y;
                acc[b][2] += xv[b] * wv.z; acc[b][3] += xv[b] * wv.w;
            }
        }
    }
    float* rr = &s_red[(w * 64 + lane) * 33];
    #pragma unroll
    for (int b = 0; b < 8; b++)
        #pragma unroll
        for (int cc = 0; cc < 4; cc++) rr[cc * 8 + b] = acc[b][cc];
    __syncthreads();
    for (int idx = tid; idx < 2048; idx += 256) {
        int b = idx >> 8, cl = idx & 255;
        int gc = cb * 256 + cl;
        if (gc < NA) {
            int ln = cl >> 2, cc = cl & 3;
            float s = s_red[(0 * 64 + ln) * 33 + cc * 8 + b]
                    + s_red[(1 * 64 + ln) * 33 + cc * 8 + b]
                    + s_red[(2 * 64 + ln) * 33 + cc * 8 + b]
                    + s_red[(3 * 64 + ln) * 33 + cc * 8 + b];
            pA[((size_t)kc * 8 + b) * NA + gc] = s;
        }
    }
}

// -------- step B: wave per (b,p): e = relu(att1+att2).Wfull (att2 from pA) ------
__global__ __launch_bounds__(256) void k_stepB(const float* __restrict__ pA,
    const float* __restrict__ bda, const float* __restrict__ att1,
    const float* __restrict__ Wf, float* __restrict__ ebuf) {
    int b  = blockIdx.x / 49;
    int p0 = (blockIdx.x % 49) * 4;
    __shared__ float a2[AA];
    __shared__ float wf[AA];
    int tid = threadIdx.x, lane = tid & 63, w = tid >> 6;
    for (int i = tid; i < AA; i += 256) {
        float s = bda[i];
        #pragma unroll 8
        for (int kc = 0; kc < KSA; kc++) s += pA[((size_t)kc * 8 + b) * NA + i];
        a2[i] = s;
        wf[i] = Wf[i];
    }
    __syncthreads();
    int p = p0 + w;
    const float* ap = att1 + (size_t)(b * PP + p) * AA;
    float s = 0.f;
    for (int f4 = lane; f4 < 175; f4 += 64) {
        float4 av = *(const float4*)(ap + f4 * 4);
        float4 tv = *(const float4*)&a2[f4 * 4];
        float4 wv = *(const float4*)&wf[f4 * 4];
        s += fmaxf(av.x + tv.x, 0.f) * wv.x + fmaxf(av.y + tv.y, 0.f) * wv.y
           + fmaxf(av.z + tv.z, 0.f) * wv.z + fmaxf(av.w + tv.w, 0.f) * wv.w;
    }
    #pragma unroll
    for (int off = 32; off; off >>= 1) s += __shfl_down(s, off, 64);
    if (lane == 0) ebuf[b * PP + p] = s;
}

// -------- step C: softmax(e) -> alpha; gate from pA; awe = gate*(alpha@enc) ----
__global__ __launch_bounds__(256) void k_stepC(const float* __restrict__ enc,
    const float* __restrict__ pA, const float* __restrict__ bfb,
    const float* __restrict__ ebuf, float* __restrict__ awe,
    float* __restrict__ oalpha, int t) {
    int b = blockIdx.x >> 3, dc = blockIdx.x & 7;
    __shared__ float s_al[PP];
    __shared__ float s_gate[256];
    __shared__ float s_red[4][256];
    __shared__ float s_rb[8];
    int tid = threadIdx.x, lane = tid & 63, w = tid >> 6;
    float v = (tid < PP) ? ebuf[b * PP + tid] : -3.4e38f;
    float m = v;
    #pragma unroll
    for (int off = 32; off; off >>= 1) m = fmaxf(m, __shfl_down(m, off, 64));
    if (lane == 0) s_rb[w] = m;
    __syncthreads();
    m = fmaxf(fmaxf(s_rb[0], s_rb[1]), fmaxf(s_rb[2], s_rb[3]));
    float ex = (tid < PP) ? expf(v - m) : 0.f;
    float s2 = ex;
    #pragma unroll
    for (int off = 32; off; off >>= 1) s2 += __shfl_down(s2, off, 64);
    if (lane == 0) s_rb[4 + w] = s2;
    __syncthreads();
    float den = s_rb[4] + s_rb[5] + s_rb[6] + s_rb[7];
    if (tid < PP) {
        float al = ex / den;
        s_al[tid] = al;
        if (dc == 0) oalpha[((size_t)b * NSTEP + t) * PP + tid] = al;
    }
    {
        int d = dc * 256 + tid;
        float g = bfb[d];
        #pragma unroll 8
        for (int kc = 0; kc < KSA; kc++) g += pA[((size_t)kc * 8 + b) * NA + AA + d];
        s_gate[tid] = sigm(g);
    }
    __syncthreads();
    int d4 = dc * 256 + lane * 4;
    const float* ep = enc + ((size_t)b * PP + w * 49) * DD + d4;
    float4 acc = make_float4(0.f, 0.f, 0.f, 0.f);
    #pragma unroll 7
    for (int p = 0; p < 49; ++p) {
        float a = s_al[w * 49 + p];
        float4 ev = *(const float4*)ep; ep += DD;
        acc.x += a * ev.x; acc.y += a * ev.y;
        acc.z += a * ev.z; acc.w += a * ev.w;
    }
    *(float4*)&s_red[w][lane * 4] = acc;
    __syncthreads();
    float tot = s_red[0][tid] + s_red[1][tid] + s_red[2][tid] + s_red[3][tid];
    awe[b * DD + dc * 256 + tid] = s_gate[tid] * tot;
}

// -------- step D1: pD[kc][b][col] partials of [emb;awe;h] @ [W_ih;W_hh] --------
__global__ __launch_bounds__(256) void k_stepD1(const float* __restrict__ emb,
    const float* __restrict__ awe, const float* __restrict__ h,
    const float* __restrict__ Wih, const float* __restrict__ Whh,
    const int* __restrict__ prev, float* __restrict__ pD) {
    __shared__ float s_X[KRD * 8];
    __shared__ float s_red[4 * 64 * 33];
    __shared__ int s_prev[8];
    int tid = threadIdx.x;
    int cb = blockIdx.x % NCBD, kc = blockIdx.x / NCBD;
    int k0 = kc * KRD;
    int kr = min(KRD, KD - k0);
    if (tid < 8) s_prev[tid] = prev[tid];
    __syncthreads();
    for (int i = tid; i < kr * 8; i += 256) {
        int k = i >> 3, b = i & 7;
        int kg = k0 + k;
        float x;
        if (kg < EE)            x = emb[(size_t)s_prev[b] * EE + kg];
        else if (kg < EE + DD)  x = awe[b * DD + (kg - EE)];
        else                    x = h[b * HH + (kg - EE - DD)];
        s_X[k * 8 + b] = x;
    }
    __syncthreads();
    int lane = tid & 63, w = tid >> 6;
    int ka = (w * kr) >> 2, kb2 = ((w + 1) * kr) >> 2;
    int c0 = cb * 256 + lane * 4;
    float acc[8][4] = {};
    if (c0 < G4) {
        #pragma unroll 2
        for (int k = ka; k < kb2; ++k) {
            int kg = k0 + k;
            const float* wp = (kg < EE + DD)
                ? (Wih + (size_t)kg * G4 + c0)
                : (Whh + (size_t)(kg - EE - DD) * G4 + c0);
            float4 wv = *(const float4*)wp;
            float4 xa = *(const float4*)&s_X[k * 8];
            float4 xb = *(const float4*)&s_X[k * 8 + 4];
            float xv[8] = {xa.x, xa.y, xa.z, xa.w, xb.x, xb.y, xb.z, xb.w};
            #pragma unroll
            for (int b = 0; b < 8; b++) {
                acc[b][0] += xv[b] * wv.x; acc[b][1] += xv[b] * wv.y;
                acc[b][2] += xv[b] * wv.z; acc[b][3] += xv[b] * wv.w;
            }
        }
    }
    float* rr = &s_red[(w * 64 + lane) * 33];
    #pragma unroll
    for (int b = 0; b < 8; b++)
        #pragma unroll
        for (int cc = 0; cc < 4; cc++) rr[cc * 8 + b] = acc[b][cc];
    __syncthreads();
    for (int idx = tid; idx < 2048; idx += 256) {
        int b = idx >> 8, cl = idx & 255;
        int gc = cb * 256 + cl;
        if (gc < G4) {
            int ln = cl >> 2, cc = cl & 3;
            float s = s_red[(0 * 64 + ln) * 33 + cc * 8 + b]
                    + s_red[(1 * 64 + ln) * 33 + cc * 8 + b]
                    + s_red[(2 * 64 + ln) * 33 + cc * 8 + b]
                    + s_red[(3 * 64 + ln) * 33 + cc * 8 + b];
            pD[((size_t)kc * 8 + b) * G4 + gc] = s;
        }
    }
}

// -------- step D2: reduce pD + biases, LSTM cell --------
__global__ __launch_bounds__(256) void k_stepD2(const float* __restrict__ pD,
    const float* __restrict__ bih, const float* __restrict__ bhh,
    float* __restrict__ c, float* __restrict__ h) {
    __shared__ float sd[4][64][4];
    int tid = threadIdx.x;
    int p = tid & 63, kcg = tid >> 6;
    int oid = blockIdx.x * 64 + p;
    float g0 = 0.f, g1 = 0.f, g2 = 0.f, g3 = 0.f;
    if (oid < BQ * HH) {
        int b = oid / HH, j = oid % HH;
        #pragma unroll
        for (int u = 0; u < 8; ++u) {
            const float* base = pD + ((size_t)(kcg * 8 + u) * 8 + b) * G4;
            g0 += base[j];          g1 += base[HH + j];
            g2 += base[2 * HH + j]; g3 += base[3 * HH + j];
        }
    }
    sd[kcg][p][0] = g0; sd[kcg][p][1] = g1;
    sd[kcg][p][2] = g2; sd[kcg][p][3] = g3;
    __syncthreads();
    if (tid < 64) {
        int oid2 = blockIdx.x * 64 + tid;
        if (oid2 < BQ * HH) {
            int b = oid2 / HH, j = oid2 % HH;
            float s0 = sd[0][tid][0] + sd[1][tid][0] + sd[2][tid][0] + sd[3][tid][0]
                     + bih[j] + bhh[j];
            float s1 = sd[0][tid][1] + sd[1][tid][1] + sd[2][tid][1] + sd[3][tid][1]
                     + bih[HH + j] + bhh[HH + j];
            float s2 = sd[0][tid][2] + sd[1][tid][2] + sd[2][tid][2] + sd[3][tid][2]
                     + bih[2 * HH + j] + bhh[2 * HH + j];
            float s3 = sd[0][tid][3] + sd[1][tid][3] + sd[2][tid][3] + sd[3][tid][3]
                     + bih[3 * HH + j] + bhh[3 * HH + j];
            float ig = sigm(s0), fg = sigm(s1), gg = tanhf(s2), og = sigm(s3);
            float cn = fg * c[b * HH + j] + ig * gg;
            c[b * HH + j] = cn;
            h[b * HH + j] = og * tanhf(cn);
        }
    }
}

// -------- step E1: pE[kc][b][col] partials of h @ W_fc --------
__global__ __launch_bounds__(256) void k_stepE1(const float* __restrict__ h,
    const float* __restrict__ Wfc, float* __restrict__ pE) {
    __shared__ float s_X[KRE * 8];
    __shared__ float s_red[4 * 64 * 33];
    int tid = threadIdx.x;
    int cb = blockIdx.x % NCBE, kc = blockIdx.x / NCBE;
    int k0 = kc * KRE;
    int kr = min(KRE, AA - k0);
    for (int i = tid; i < kr * 8; i += 256) {
        int k = i >> 3, b = i & 7;
        s_X[k * 8 + b] = h[b * HH + k0 + k];
    }
    __syncthreads();
    int lane = tid & 63, w = tid >> 6;
    int ka = (w * kr) >> 2, kb = ((w + 1) * kr) >> 2;
    int c0 = cb * 256 + lane * 4;
    float acc[8][4] = {};
    if (c0 < VV) {
        const float* wp = Wfc + (size_t)(k0 + ka) * VV + c0;
        #pragma unroll 2
        for (int k = ka; k < kb; ++k) {
            float4 wv = *(const float4*)wp; wp += VV;
            float4 xa = *(const float4*)&s_X[k * 8];
            float4 xb = *(const float4*)&s_X[k * 8 + 4];
            float xv[8] = {xa.x, xa.y, xa.z, xa.w, xb.x, xb.y, xb.z, xb.w};
            #pragma unroll
            for (int b = 0; b < 8; b++) {
                acc[b][0] += xv[b] * wv.x; acc[b][1] += xv[b] * wv.y;
                acc[b][2] += xv[b] * wv.z; acc[b][3] += xv[b] * wv.w;
            }
        }
    }
    float* rr = &s_red[(w * 64 + lane) * 33];
    #pragma unroll
    for (int b = 0; b < 8; b++)
        #pragma unroll
        for (int cc = 0; cc < 4; cc++) rr[cc * 8 + b] = acc[b][cc];
    __syncthreads();
    for (int idx = tid; idx < 2048; idx += 256) {
        int b = idx >> 8, cl = idx & 255;
        int gc = cb * 256 + cl;
        if (gc < VV) {
            int ln = cl >> 2, cc = cl & 3;
            float s = s_red[(0 * 64 + ln) * 33 + cc * 8 + b]
                    + s_red[(1 * 64 + ln) * 33 + cc * 8 + b]
                    + s_red[(2 * 64 + ln) * 33 + cc * 8 + b]
                    + s_red[(3 * 64 + ln) * 33 + cc * 8 + b];
            pE[((size_t)kc * 8 + b) * VV + gc] = s;
        }
    }
}

// -------- step E2: reduce pE + b_fc -> preds, per-block argmax partials --------
__global__ __launch_bounds__(256) void k_stepE2(const float* __restrict__ pE,
    const float* __restrict__ bfc, float* __restrict__ preds,
    float* __restrict__ argval, int* __restrict__ argidx, int t) {
    __shared__ float lg[128][8];
    int tid = threadIdx.x;
    int base = blockIdx.x * 128;
    for (int idx = tid; idx < 1024; idx += 256) {
        int b = idx >> 7, cl = idx & 127;
        int col = base + cl;
        float s = -3.4e38f;
        if (col < VV) {
            s = bfc[col];
            #pragma unroll
            for (int kc = 0; kc < KSE; kc++)
                s += pE[((size_t)kc * 8 + b) * VV + col];
            preds[((size_t)b * NSTEP + t) * VV + col] = s;
        }
        lg[cl][b] = s;
    }
    __syncthreads();
    int b = tid >> 5, l = tid & 31;
    float bv = -3.4e38f; int bi = 0x7fffffff;
    for (int cl = l; cl < 128; cl += 32) {
        float v = lg[cl][b];
        int gi = base + cl;
        if (v > bv || (v == bv && gi < bi)) { bv = v; bi = gi; }
    }
    #pragma unroll
    for (int off = 16; off; off >>= 1) {
        float ov = __shfl_down(bv, off, 32);
        int   oi = __shfl_down(bi, off, 32);
        if (ov > bv || (ov == bv && oi < bi)) { bv = ov; bi = oi; }
    }
    if (l == 0) { argval[blockIdx.x * 8 + b] = bv; argidx[blockIdx.x * 8 + b] = bi; }
}

extern "C" void kernel_launch(void* const* d_in, const int* in_sizes, int n_in,
                              void* d_out, int out_size, void* d_ws, size_t ws_size,
                              hipStream_t stream) {
    (void)in_sizes; (void)n_in; (void)out_size; (void)ws_size;
    const float* enc   = (const float*)d_in[0];
    const float* emb   = (const float*)d_in[2];
    const float* Wea   = (const float*)d_in[3];
    const float* bea   = (const float*)d_in[4];
    const float* Wda   = (const float*)d_in[5];
    const float* bda   = (const float*)d_in[6];
    const float* Wfull = (const float*)d_in[7];
    // d_in[8] = b_full (softmax-invariant, unused)
    const float* Wih   = (const float*)d_in[9];
    const float* bih   = (const float*)d_in[10];
    const float* Whh   = (const float*)d_in[11];
    const float* bhh   = (const float*)d_in[12];
    const float* Winh  = (const float*)d_in[13];
    const float* binh  = (const float*)d_in[14];
    const float* Winc  = (const float*)d_in[15];
    const float* binc  = (const float*)d_in[16];
    const float* Wfb   = (const float*)d_in[17];
    const float* bfb   = (const float*)d_in[18];
    const float* Wfc   = (const float*)d_in[19];
    const float* bfc   = (const float*)d_in[20];

    float* preds  = (float*)d_out;
    float* oalpha = preds + (size_t)BQ * NSTEP * VV;

    float* ws = (float*)d_ws;
    float* att1   = ws; ws += (size_t)BQ * PP * AA;    // 1,097,600
    float* pA     = ws; ws += (size_t)KSA * 8 * NA;    //   703,488
    float* pDE    = ws; ws += (size_t)KSE * 8 * VV;    // 1,440,000 (also att1 k-partial, pD)
    float* mean   = ws; ws += BQ * DD;
    float* hbuf   = ws; ws += BQ * HH;
    float* cbuf   = ws; ws += BQ * HH;
    float* ebuf   = ws; ws += BQ * PP;
    float* awe    = ws; ws += BQ * DD;
    float* argval = ws; ws += NB2 * 8;
    int*   argidx = (int*)ws; ws += NB2 * 8;
    int*   prev   = (int*)ws; ws += 16;

    k_mean<<<64, 256, 0, stream>>>(enc, mean);
    k_init_hc<<<22, 256, 0, stream>>>(mean, Winh, binh, Winc, binc, hbuf, cbuf);
    k_att1<<<dim3(25, 11, 2), 256, 0, stream>>>(enc, Wea, att1, pDE);
    k_att1red<<<BQ * PP, 256, 0, stream>>>(att1, pDE, bea);

    for (int t = 0; t < NSTEP; t++) {
        k_stepA<<<NCBA * KSA + 1, 256, 0, stream>>>(hbuf, Wda, Wfb, pA,
                                                    argval, argidx, prev, t);
        k_stepB<<<392, 256, 0, stream>>>(pA, bda, att1, Wfull, ebuf);
        k_stepC<<<64, 256, 0, stream>>>(enc, pA, bfb, ebuf, awe, oalpha, t);
        k_stepD1<<<NCBD * KSD, 256, 0, stream>>>(emb, awe, hbuf, Wih, Whh, prev, pDE);
        k_stepD2<<<88, 256, 0, stream>>>(pDE, bih, bhh, cbuf, hbuf);
        k_stepE1<<<NCBE * KSE, 256, 0, stream>>>(hbuf, Wfc, pDE);
        k_stepE2<<<NB2, 256, 0, stream>>>(pDE, bfc, preds, argval, argidx, t);
    }
}